// Round 2
// baseline (1487.709 us; speedup 1.0000x reference)
//
#include <hip/hip_runtime.h>

#define NN 50000
#define NE 1600000
#define DF 128

// K1: one 64-lane wave per node.
// rinv[i] = rsqrt(max(sum x^2, (1e-12)^2)); s[i] seeded with self-loop term exp(beta - |beta|).
// (Softmax shifted by |beta| instead of segment_max: cos-sim logits are in [-|beta|, |beta|],
//  shift-invariance makes this exact, and the self-loop term keeps s >= exp(-2|beta|) > 0.)
__global__ void k_norm(const float* __restrict__ x,
                       const float* __restrict__ beta_p,
                       float* __restrict__ rinv, float* __restrict__ s) {
    int wave = (blockIdx.x * blockDim.x + threadIdx.x) >> 6;
    int lane = threadIdx.x & 63;
    if (wave >= NN) return;
    float2 v = ((const float2*)(x + (size_t)wave * DF))[lane];
    float acc = v.x * v.x + v.y * v.y;
    #pragma unroll
    for (int m = 1; m < 64; m <<= 1) acc += __shfl_xor(acc, m);
    if (lane == 0) {
        rinv[wave] = rsqrtf(fmaxf(acc, 1e-24f));
        float b = beta_p[0];
        s[wave] = __expf(b - fabsf(b));
    }
}

// K2 (fused): one wave per edge. Butterfly all-reduce of dot(x_src, x_dst); every lane then
// holds e = exp(beta*cos - |beta|). Lane 0 adds e into the softmax denom s[dst]; all lanes
// scatter the UNNORMALIZED message e * x_src into out[dst] (contiguous 8B/lane atomics).
__global__ void k_edge_scatter(const float* __restrict__ x,
                               const int* __restrict__ ei,
                               const float* __restrict__ beta_p,
                               const float* __restrict__ rinv,
                               float* __restrict__ s,
                               float* __restrict__ out) {
    int edge = (blockIdx.x * blockDim.x + threadIdx.x) >> 6;
    int lane = threadIdx.x & 63;
    if (edge >= NE) return;
    int src = ei[edge];
    int dst = ei[NE + edge];
    float2 a = ((const float2*)(x + (size_t)src * DF))[lane];
    float2 b = ((const float2*)(x + (size_t)dst * DF))[lane];
    float dot = fmaf(a.x, b.x, a.y * b.y);
    #pragma unroll
    for (int m = 1; m < 64; m <<= 1) dot += __shfl_xor(dot, m);
    float beta = beta_p[0];
    float logit = beta * rinv[src] * rinv[dst] * dot;
    float e = __expf(logit - fabsf(beta));
    if (lane == 0) atomicAdd(&s[dst], e);
    float* op = out + (size_t)dst * DF + 2 * lane;
    atomicAdd(op,     e * a.x);
    atomicAdd(op + 1, e * a.y);
}

// K3: out[i] = relu((out[i] + e_self * x[i]) / s[i]). One wave per node, in place.
__global__ void k_final(const float* __restrict__ x,
                        const float* __restrict__ beta_p,
                        const float* __restrict__ s,
                        float* __restrict__ out) {
    int wave = (blockIdx.x * blockDim.x + threadIdx.x) >> 6;
    int lane = threadIdx.x & 63;
    if (wave >= NN) return;
    float b = beta_p[0];
    float es = __expf(b - fabsf(b));          // self-loop weight (cos = 1)
    float inv = 1.0f / s[wave];
    float2 xv = ((const float2*)(x + (size_t)wave * DF))[lane];
    float2* op = (float2*)(out + (size_t)wave * DF) + lane;
    float2 a = *op;
    float2 o;
    o.x = fmaxf(0.f, (a.x + es * xv.x) * inv);
    o.y = fmaxf(0.f, (a.y + es * xv.y) * inv);
    *op = o;
}

extern "C" void kernel_launch(void* const* d_in, const int* in_sizes, int n_in,
                              void* d_out, int out_size, void* d_ws, size_t ws_size,
                              hipStream_t stream) {
    const float* x    = (const float*)d_in[0];   // fp32 [NN*DF]
    const float* beta = (const float*)d_in[1];   // fp32 [1]
    const int*   ei   = (const int*)d_in[2];     // int32 [2*NE] (row 0 = src, row 1 = dst)
    float*       out  = (float*)d_out;           // fp32 [NN*DF]

    // workspace: rinv (NN floats) + s (NN floats) = 400 KB
    float* rinv = (float*)d_ws;
    float* s    = (float*)d_ws + NN;

    // out is poisoned before every timed launch -> we accumulate into it, so zero it first.
    hipMemsetAsync(out, 0, (size_t)NN * DF * sizeof(float), stream);

    {   // K1: 1 wave/node
        int blocks = (NN * 64 + 255) / 256;
        k_norm<<<blocks, 256, 0, stream>>>(x, beta, rinv, s);
    }
    {   // K2: 1 wave/edge (fused logit + scatter)
        int blocks = (int)(((size_t)NE * 64 + 255) / 256);
        k_edge_scatter<<<blocks, 256, 0, stream>>>(x, ei, beta, rinv, s, out);
    }
    {   // K3: 1 wave/node
        int blocks = (NN * 64 + 255) / 256;
        k_final<<<blocks, 256, 0, stream>>>(x, beta, s, out);
    }
}

// Round 3
// 494.716 us; speedup vs baseline: 3.0072x; 3.0072x over previous
//
#include <hip/hip_runtime.h>

#define NN 50000
#define NE 1600000
#define DF 128
#define SEG 250     // elements per scan block
#define NBLK 200    // SEG * NBLK == NN

// ---------------------------------------------------------------------------
// K1: one 64-lane wave per node.
//   xn[i,:]  = x[i,:] * rsqrt(max(||x||^2, eps^2))   (normalized row)
//   norm[i]  = ||x||^2 * rsqrt(...) == ||x|| (smoothly ->0 for near-zero rows)
// Softmax is shifted by the constant |beta| instead of segment_max (logits are
// beta*cos in [-|beta|,|beta|]; shift-invariance makes this exact, self-loop
// keeps every denominator >= exp(-2|beta|) > 0).
// ---------------------------------------------------------------------------
__global__ void k_norm(const float* __restrict__ x,
                       float* __restrict__ xn, float* __restrict__ norm) {
    int wave = (blockIdx.x * blockDim.x + threadIdx.x) >> 6;
    int lane = threadIdx.x & 63;
    if (wave >= NN) return;
    float2 v = ((const float2*)(x + (size_t)wave * DF))[lane];
    float ss = v.x * v.x + v.y * v.y;
    #pragma unroll
    for (int m = 1; m < 64; m <<= 1) ss += __shfl_xor(ss, m);   // all lanes get total
    float rinv = rsqrtf(fmaxf(ss, 1e-24f));
    float2 o; o.x = v.x * rinv; o.y = v.y * rinv;
    ((float2*)(xn + (size_t)wave * DF))[lane] = o;
    if (lane == 0) norm[wave] = ss * rinv;
}

// K2: histogram of in-degrees (int atomics, ~32-way mean contention).
__global__ void k_hist(const int* __restrict__ ei, int* __restrict__ deg) {
    int e = blockIdx.x * blockDim.x + threadIdx.x;
    if (e >= NE) return;
    atomicAdd(&deg[ei[NE + e]], 1);
}

// K3a: per-block partial sums of deg (NBLK blocks x SEG elements).
__global__ void k_scan_a(const int* __restrict__ deg, int* __restrict__ partial) {
    __shared__ int wsum[4];
    int b = blockIdx.x, t = threadIdx.x;
    int v = (t < SEG) ? deg[b * SEG + t] : 0;
    #pragma unroll
    for (int m = 1; m < 64; m <<= 1) v += __shfl_xor(v, m);
    if ((t & 63) == 0) wsum[t >> 6] = v;
    __syncthreads();
    if (t == 0) partial[b] = wsum[0] + wsum[1] + wsum[2] + wsum[3];
}

// K3b: exclusive scan of the NBLK partials (sequential, tiny).
__global__ void k_scan_b(int* __restrict__ partial, int* __restrict__ row_ptr) {
    int run = 0;
    for (int j = 0; j < NBLK; ++j) { int t = partial[j]; partial[j] = run; run += t; }
    row_ptr[NN] = run;   // == NE
}

// K3c: per-block exclusive scan of deg chunk + offset; writes row_ptr and a
// second copy (cur) used as fill cursors by k_fill.
__global__ void k_scan_c(const int* __restrict__ deg, const int* __restrict__ partial,
                         int* __restrict__ row_ptr, int* __restrict__ cur) {
    __shared__ int sm[256];
    int b = blockIdx.x, t = threadIdx.x;
    int own = (t < SEG) ? deg[b * SEG + t] : 0;
    sm[t] = own;
    __syncthreads();
    #pragma unroll
    for (int off = 1; off < 256; off <<= 1) {
        int add = (t >= off) ? sm[t - off] : 0;
        __syncthreads();
        sm[t] += add;
        __syncthreads();
    }
    if (t < SEG) {
        int excl = partial[b] + sm[t] - own;
        int idx = b * SEG + t;
        row_ptr[idx] = excl;
        cur[idx] = excl;
    }
}

// K4: bucket-fill — col[pos] = src for each edge, pos from the dst cursor.
__global__ void k_fill(const int* __restrict__ ei, int* __restrict__ cur,
                       int* __restrict__ col) {
    int e = blockIdx.x * blockDim.x + threadIdx.x;
    if (e >= NE) return;
    int src = ei[e];
    int dst = ei[NE + e];
    int pos = atomicAdd(&cur[dst], 1);
    col[pos] = src;
}

// K5: one wave per dst node. Walk in-edges; dot via butterfly; accumulate the
// softmax denominator and the unnormalized message sum in registers. No atomics.
__global__ void k_gather(const float* __restrict__ xn,
                         const float* __restrict__ norm,
                         const int* __restrict__ row_ptr,
                         const int* __restrict__ col,
                         const float* __restrict__ beta_p,
                         float* __restrict__ out) {
    int wave = (blockIdx.x * blockDim.x + threadIdx.x) >> 6;
    int lane = threadIdx.x & 63;
    if (wave >= NN) return;
    float beta = beta_p[0];
    float c = -fabsf(beta);
    float2 xd = ((const float2*)(xn + (size_t)wave * DF))[lane];

    // self-loop: logit = beta (cos=1), message = e_self * x_dst
    float e_self = __expf(beta + c);
    float ssum = e_self;
    float wd = e_self * norm[wave];
    float2 acc; acc.x = wd * xd.x; acc.y = wd * xd.y;

    int b0 = row_ptr[wave], b1 = row_ptr[wave + 1];
    for (int k = b0; k < b1; ++k) {
        int src = col[k];                                   // wave-uniform
        float2 xs = ((const float2*)(xn + (size_t)src * DF))[lane];
        float nrm = norm[src];                              // wave-uniform
        float dot = fmaf(xd.x, xs.x, xd.y * xs.y);
        #pragma unroll
        for (int m = 1; m < 64; m <<= 1) dot += __shfl_xor(dot, m);
        float e = __expf(fmaf(beta, dot, c));
        ssum += e;
        float w = e * nrm;
        acc.x = fmaf(w, xs.x, acc.x);
        acc.y = fmaf(w, xs.y, acc.y);
    }
    float inv = 1.0f / ssum;
    float2 o;
    o.x = fmaxf(0.f, acc.x * inv);
    o.y = fmaxf(0.f, acc.y * inv);
    ((float2*)(out + (size_t)wave * DF))[lane] = o;
}

extern "C" void kernel_launch(void* const* d_in, const int* in_sizes, int n_in,
                              void* d_out, int out_size, void* d_ws, size_t ws_size,
                              hipStream_t stream) {
    const float* x    = (const float*)d_in[0];   // fp32 [NN*DF]
    const float* beta = (const float*)d_in[1];   // fp32 [1]
    const int*   ei   = (const int*)d_in[2];     // int32 [2*NE]
    float*       out  = (float*)d_out;           // fp32 [NN*DF]

    // workspace layout (bytes), total ~31.3 MiB:
    char* ws = (char*)d_ws;
    float* xn      = (float*)ws;                            // NN*DF*4 = 25,600,000
    float* norm    = (float*)(ws + 25600000);               // NN*4    =    200,000
    int*   deg     = (int*)  (ws + 25800000);               // NN*4
    int*   cur     = (int*)  (ws + 26000000);               // NN*4
    int*   row_ptr = (int*)  (ws + 26200000);               // (NN+1)*4
    int*   partial = (int*)  (ws + 26400208);               // NBLK*4
    int*   col     = (int*)  (ws + 26401024);               // NE*4 = 6,400,000

    hipMemsetAsync(deg, 0, (size_t)NN * sizeof(int), stream);

    k_norm  <<<(NN * 64 + 255) / 256, 256, 0, stream>>>(x, xn, norm);
    k_hist  <<<(NE + 255) / 256,      256, 0, stream>>>(ei, deg);
    k_scan_a<<<NBLK,                  256, 0, stream>>>(deg, partial);
    k_scan_b<<<1,                       1, 0, stream>>>(partial, row_ptr);
    k_scan_c<<<NBLK,                  256, 0, stream>>>(deg, partial, row_ptr, cur);
    k_fill  <<<(NE + 255) / 256,      256, 0, stream>>>(ei, cur, col);
    k_gather<<<(NN * 64 + 255) / 256, 256, 0, stream>>>(xn, norm, row_ptr, col, beta, out);
}

// Round 4
// 346.166 us; speedup vs baseline: 4.2977x; 1.4291x over previous
//
#include <hip/hip_runtime.h>

#define NN 50000
#define NE 1600000
#define DF 128
#define SEG 250     // elements per scan block
#define NBLK 200    // SEG * NBLK == NN
#define NBN 12500   // norm blocks: NN waves, 4 waves/block
#define NBH 6250    // hist blocks: NE threads / 256

static __device__ __forceinline__ float bflo(unsigned int u) {
    unsigned int v = u << 16; float f; __builtin_memcpy(&f, &v, 4); return f;
}
static __device__ __forceinline__ float bfhi(unsigned int u) {
    unsigned int v = u & 0xFFFF0000u; float f; __builtin_memcpy(&f, &v, 4); return f;
}
static __device__ __forceinline__ unsigned int f2bf(float f) {   // RNE, returns low 16
    unsigned int u; __builtin_memcpy(&u, &f, 4);
    u += 0x7FFFu + ((u >> 16) & 1u);
    return u >> 16;
}

// ---------------------------------------------------------------------------
// K1 (fused): blocks [0,NBN) -> row-normalize x into bf16-packed xn_bf + norm;
//             blocks [NBN,NBN+NBH) -> in-degree histogram (deg pre-zeroed).
// Softmax is shifted by the constant |beta| instead of segment_max (logits are
// beta*cos in [-|beta|,|beta|]; exact by shift-invariance; self-loop keeps
// every denominator >= exp(-2|beta|) > 0).
// ---------------------------------------------------------------------------
__global__ void k_norm_hist(const float* __restrict__ x,
                            const int* __restrict__ ei,
                            unsigned int* __restrict__ xn_bf,   // NN x 64 uints
                            float* __restrict__ norm,
                            int* __restrict__ deg) {
    if (blockIdx.x < NBN) {
        int wave = (blockIdx.x * 256 + threadIdx.x) >> 6;
        int lane = threadIdx.x & 63;
        if (wave >= NN) return;
        float2 v = ((const float2*)(x + (size_t)wave * DF))[lane];
        float ss = v.x * v.x + v.y * v.y;
        #pragma unroll
        for (int m = 1; m < 64; m <<= 1) ss += __shfl_xor(ss, m);
        float rinv = rsqrtf(fmaxf(ss, 1e-24f));
        unsigned int p = (f2bf(v.y * rinv) << 16) | f2bf(v.x * rinv);
        xn_bf[(size_t)wave * 64 + lane] = p;
        if (lane == 0) norm[wave] = ss * rinv;     // == ||x|| (smooth at 0)
    } else {
        int e = (blockIdx.x - NBN) * 256 + threadIdx.x;
        if (e >= NE) return;
        atomicAdd(&deg[ei[NE + e]], 1);
    }
}

// K2a: per-block partial sums of deg (NBLK blocks x SEG elements).
__global__ void k_scan_a(const int* __restrict__ deg, int* __restrict__ partial) {
    __shared__ int wsum[4];
    int b = blockIdx.x, t = threadIdx.x;
    int v = (t < SEG) ? deg[b * SEG + t] : 0;
    #pragma unroll
    for (int m = 1; m < 64; m <<= 1) v += __shfl_xor(v, m);
    if ((t & 63) == 0) wsum[t >> 6] = v;
    __syncthreads();
    if (t == 0) partial[b] = wsum[0] + wsum[1] + wsum[2] + wsum[3];
}

// K2b: exclusive scan of the NBLK partials — one block, LDS Hillis-Steele.
__global__ void k_scan_b(int* __restrict__ partial, int* __restrict__ row_ptr) {
    __shared__ int sm[256];
    int t = threadIdx.x;
    int v = (t < NBLK) ? partial[t] : 0;
    sm[t] = v;
    __syncthreads();
    #pragma unroll
    for (int off = 1; off < 256; off <<= 1) {
        int add = (t >= off) ? sm[t - off] : 0;
        __syncthreads();
        sm[t] += add;
        __syncthreads();
    }
    if (t < NBLK) partial[t] = sm[t] - v;          // exclusive
    if (t == 0) row_ptr[NN] = NE;                  // total degree is exactly NE
}

// K2c: per-block exclusive scan of deg chunk + block offset -> row_ptr & cursors.
__global__ void k_scan_c(const int* __restrict__ deg, const int* __restrict__ partial,
                         int* __restrict__ row_ptr, int* __restrict__ cur) {
    __shared__ int sm[256];
    int b = blockIdx.x, t = threadIdx.x;
    int own = (t < SEG) ? deg[b * SEG + t] : 0;
    sm[t] = own;
    __syncthreads();
    #pragma unroll
    for (int off = 1; off < 256; off <<= 1) {
        int add = (t >= off) ? sm[t - off] : 0;
        __syncthreads();
        sm[t] += add;
        __syncthreads();
    }
    if (t < SEG) {
        int excl = partial[b] + sm[t] - own;
        int idx = b * SEG + t;
        row_ptr[idx] = excl;
        cur[idx] = excl;
    }
}

// K3: bucket-fill — col[pos] = src for each edge, pos from the dst cursor.
__global__ void k_fill(const int* __restrict__ ei, int* __restrict__ cur,
                       int* __restrict__ col) {
    int e = blockIdx.x * blockDim.x + threadIdx.x;
    if (e >= NE) return;
    int src = ei[e];
    int dst = ei[NE + e];
    int pos = atomicAdd(&cur[dst], 1);
    col[pos] = src;
}

// K4: one wave per dst node, 4 groups of 16 lanes; group g walks edges
// b0+g, b0+g+4, ... Each lane owns 8 row elements (16B bf16 load per edge).
// 4 independent row-gathers in flight per wave-iteration; 4-step butterfly.
__global__ void k_gather(const unsigned int* __restrict__ xn_bf,
                         const float* __restrict__ norm,
                         const int* __restrict__ row_ptr,
                         const int* __restrict__ col,
                         const float* __restrict__ beta_p,
                         float* __restrict__ out) {
    int wave = (blockIdx.x * blockDim.x + threadIdx.x) >> 6;
    int lane = threadIdx.x & 63;
    if (wave >= NN) return;
    int j = lane & 15;          // element-chunk id within row
    int g = lane >> 4;          // edge group
    float beta = beta_p[0];
    float c = -fabsf(beta);

    // dst row chunk: elements [8j, 8j+8)
    uint4 du = ((const uint4*)(xn_bf + (size_t)wave * 64))[j];
    float xd[8];
    #pragma unroll
    for (int q = 0; q < 4; ++q) {
        unsigned int u = (&du.x)[q];
        xd[2 * q]     = bflo(u);
        xd[2 * q + 1] = bfhi(u);
    }

    float acc[8] = {0.f, 0.f, 0.f, 0.f, 0.f, 0.f, 0.f, 0.f};
    float ssum = 0.f;
    int b0 = row_ptr[wave], b1 = row_ptr[wave + 1];

    #pragma unroll 2
    for (int k = b0 + g; k < b1; k += 4) {
        int src = col[k];                                    // group-uniform
        uint4 su = ((const uint4*)(xn_bf + (size_t)src * 64))[j];
        float nrm = norm[src];                               // group-uniform
        float xs[8];
        #pragma unroll
        for (int q = 0; q < 4; ++q) {
            unsigned int u = (&su.x)[q];
            xs[2 * q]     = bflo(u);
            xs[2 * q + 1] = bfhi(u);
        }
        float dot = 0.f;
        #pragma unroll
        for (int q = 0; q < 8; ++q) dot = fmaf(xd[q], xs[q], dot);
        dot += __shfl_xor(dot, 1);
        dot += __shfl_xor(dot, 2);
        dot += __shfl_xor(dot, 4);
        dot += __shfl_xor(dot, 8);                           // all 16 lanes have it
        float e = __expf(fmaf(beta, dot, c));
        ssum += e;
        float w = e * nrm;
        #pragma unroll
        for (int q = 0; q < 8; ++q) acc[q] = fmaf(w, xs[q], acc[q]);
    }

    // combine the 4 groups (each holds the same 8 elements for its edges)
    ssum += __shfl_xor(ssum, 16);
    ssum += __shfl_xor(ssum, 32);
    #pragma unroll
    for (int q = 0; q < 8; ++q) {
        acc[q] += __shfl_xor(acc[q], 16);
        acc[q] += __shfl_xor(acc[q], 32);
    }

    // self-loop (cos = 1): e_self = exp(beta - |beta|), message e_self * x_dst
    float e_self = __expf(beta + c);
    ssum += e_self;
    float wsl = e_self * norm[wave];
    #pragma unroll
    for (int q = 0; q < 8; ++q) acc[q] = fmaf(wsl, xd[q], acc[q]);

    if (g == 0) {
        float inv = 1.0f / ssum;
        float4 o0, o1;
        o0.x = fmaxf(0.f, acc[0] * inv); o0.y = fmaxf(0.f, acc[1] * inv);
        o0.z = fmaxf(0.f, acc[2] * inv); o0.w = fmaxf(0.f, acc[3] * inv);
        o1.x = fmaxf(0.f, acc[4] * inv); o1.y = fmaxf(0.f, acc[5] * inv);
        o1.z = fmaxf(0.f, acc[6] * inv); o1.w = fmaxf(0.f, acc[7] * inv);
        float4* op = (float4*)(out + (size_t)wave * DF + 8 * j);
        op[0] = o0;
        op[1] = o1;
    }
}

extern "C" void kernel_launch(void* const* d_in, const int* in_sizes, int n_in,
                              void* d_out, int out_size, void* d_ws, size_t ws_size,
                              hipStream_t stream) {
    const float* x    = (const float*)d_in[0];   // fp32 [NN*DF]
    const float* beta = (const float*)d_in[1];   // fp32 [1]
    const int*   ei   = (const int*)d_in[2];     // int32 [2*NE]
    float*       out  = (float*)d_out;           // fp32 [NN*DF]

    // workspace layout (bytes), total ~20.0 MiB:
    char* ws = (char*)d_ws;
    unsigned int* xn_bf = (unsigned int*)ws;                 // NN*64*4 = 12,800,000
    float* norm    = (float*)(ws + 12800000);                // NN*4
    int*   deg     = (int*)  (ws + 13000000);                // NN*4
    int*   cur     = (int*)  (ws + 13200000);                // NN*4
    int*   row_ptr = (int*)  (ws + 13400000);                // (NN+1)*4
    int*   partial = (int*)  (ws + 13600016);                // NBLK*4
    int*   col     = (int*)  (ws + 13600816);                // NE*4 = 6,400,000

    hipMemsetAsync(deg, 0, (size_t)NN * sizeof(int), stream);

    k_norm_hist<<<NBN + NBH,            256, 0, stream>>>(x, ei, xn_bf, norm, deg);
    k_scan_a   <<<NBLK,                 256, 0, stream>>>(deg, partial);
    k_scan_b   <<<1,                    256, 0, stream>>>(partial, row_ptr);
    k_scan_c   <<<NBLK,                 256, 0, stream>>>(deg, partial, row_ptr, cur);
    k_fill     <<<(NE + 255) / 256,     256, 0, stream>>>(ei, cur, col);
    k_gather   <<<(NN * 64 + 255) / 256, 256, 0, stream>>>(xn_bf, norm, row_ptr, col, beta, out);
}

// Round 5
// 198.281 us; speedup vs baseline: 7.5030x; 1.7458x over previous
//
#include <hip/hip_runtime.h>

#define NN 50000
#define NE 1600000
#define DF 128
#define NB 250      // coarse buckets
#define BSZ 200     // dst nodes per bucket  (NB*BSZ == NN)
#define NWG 512     // partition workgroups
#define CHK 3125    // edges per partition wg (NWG*CHK == NE)

static __device__ __forceinline__ float bflo(unsigned int u) {
    unsigned int v = u << 16; float f; __builtin_memcpy(&f, &v, 4); return f;
}
static __device__ __forceinline__ float bfhi(unsigned int u) {
    unsigned int v = u & 0xFFFF0000u; float f; __builtin_memcpy(&f, &v, 4); return f;
}
static __device__ __forceinline__ unsigned int f2bf(float f) {   // RNE, low 16 bits
    unsigned int u; __builtin_memcpy(&u, &f, 4);
    u += 0x7FFFu + ((u >> 16) & 1u);
    return u >> 16;
}

// ---------------------------------------------------------------------------
// K1: one wave per node: xn_bf[i,:] = bf16(x[i,:] * rsqrt(max(||x||^2,eps^2))),
// norm[i] = ||x|| (smooth ->0 for zero rows). Softmax later shifts by the
// constant |beta| (exact: logits beta*cos in [-|beta|,|beta|]; self-loop keeps
// every denominator >= exp(-2|beta|) > 0).
// ---------------------------------------------------------------------------
__global__ void k_norm(const float* __restrict__ x,
                       unsigned int* __restrict__ xn_bf,
                       float* __restrict__ norm) {
    int wave = (blockIdx.x * blockDim.x + threadIdx.x) >> 6;
    int lane = threadIdx.x & 63;
    if (wave >= NN) return;
    float2 v = ((const float2*)(x + (size_t)wave * DF))[lane];
    float ss = v.x * v.x + v.y * v.y;
    #pragma unroll
    for (int m = 1; m < 64; m <<= 1) ss += __shfl_xor(ss, m);
    float rinv = rsqrtf(fmaxf(ss, 1e-24f));
    xn_bf[(size_t)wave * 64 + lane] = (f2bf(v.y * rinv) << 16) | f2bf(v.x * rinv);
    if (lane == 0) norm[wave] = ss * rinv;
}

// K2: per-wg LDS histogram over coarse buckets (dst/BSZ). No global atomics.
__global__ void k_count(const int* __restrict__ ei_dst, int* __restrict__ whist) {
    __shared__ int h[NB];
    int wg = blockIdx.x, t = threadIdx.x;
    for (int i = t; i < NB; i += 256) h[i] = 0;
    __syncthreads();
    int c0 = wg * CHK;
    for (int i = t; i < CHK; i += 256) atomicAdd(&h[ei_dst[c0 + i] / BSZ], 1);
    __syncthreads();
    for (int i = t; i < NB; i += 256) whist[i * NWG + wg] = h[i];
}

// K3a: per-bucket exclusive scan across the 512 wg counts (512-thread blocks).
__global__ void k_scan_wg(int* __restrict__ whist, int* __restrict__ btotal) {
    __shared__ int sm[NWG];
    int b = blockIdx.x, t = threadIdx.x;
    int v = whist[b * NWG + t];
    sm[t] = v;
    __syncthreads();
    #pragma unroll
    for (int off = 1; off < NWG; off <<= 1) {
        int a = (t >= off) ? sm[t - off] : 0;
        __syncthreads();
        sm[t] += a;
        __syncthreads();
    }
    whist[b * NWG + t] = sm[t] - v;          // exclusive within bucket
    if (t == NWG - 1) btotal[b] = sm[t];
}

// K3b: exclusive scan of the 250 bucket totals.
__global__ void k_scan_bk(const int* __restrict__ btotal, int* __restrict__ bbase,
                          int* __restrict__ row_ptr) {
    __shared__ int sm[256];
    int t = threadIdx.x;
    int v = (t < NB) ? btotal[t] : 0;
    sm[t] = v;
    __syncthreads();
    #pragma unroll
    for (int off = 1; off < 256; off <<= 1) {
        int a = (t >= off) ? sm[t - off] : 0;
        __syncthreads();
        sm[t] += a;
        __syncthreads();
    }
    if (t < NB) bbase[t] = sm[t] - v;
    if (t == 0) row_ptr[NN] = NE;
}

// K4: partition edges into bucket-sorted packed records (local_dst<<16 | src).
// Each (wg,bucket) sub-region is exclusively owned -> LDS cursors only, and the
// 4B stores fill lines in L2 before writeback (no 16x write amplification).
__global__ void k_part(const int* __restrict__ ei, const int* __restrict__ whist,
                       const int* __restrict__ bbase, unsigned int* __restrict__ pairs) {
    __shared__ int cur[NB];
    int wg = blockIdx.x, t = threadIdx.x;
    for (int i = t; i < NB; i += 256) cur[i] = bbase[i] + whist[i * NWG + wg];
    __syncthreads();
    int c0 = wg * CHK;
    for (int i = t; i < CHK; i += 256) {
        int src = ei[c0 + i];
        int dst = ei[NE + c0 + i];
        int b = dst / BSZ;
        int pos = atomicAdd(&cur[b], 1);
        pairs[pos] = ((unsigned int)(dst - b * BSZ) << 16) | (unsigned int)src;
    }
}

// K5: one wg per bucket: LDS hist over its 200 dst, LDS scan -> row_ptr, then
// LDS-cursor fill of col within the bucket's private window. No global atomics.
__global__ void k_build(const unsigned int* __restrict__ pairs,
                        const int* __restrict__ bbase,
                        int* __restrict__ row_ptr, int* __restrict__ col) {
    __shared__ int h[BSZ];
    __shared__ int sc[256];
    int b = blockIdx.x, t = threadIdx.x;
    int base = bbase[b];
    int end  = (b == NB - 1) ? NE : bbase[b + 1];
    for (int i = t; i < BSZ; i += 256) h[i] = 0;
    __syncthreads();
    for (int i = base + t; i < end; i += 256) atomicAdd(&h[pairs[i] >> 16], 1);
    __syncthreads();
    int own = (t < BSZ) ? h[t] : 0;
    sc[t] = own;
    __syncthreads();
    #pragma unroll
    for (int off = 1; off < 256; off <<= 1) {
        int a = (t >= off) ? sc[t - off] : 0;
        __syncthreads();
        sc[t] += a;
        __syncthreads();
    }
    if (t < BSZ) {
        int excl = base + sc[t] - own;
        row_ptr[b * BSZ + t] = excl;
        h[t] = excl;                         // becomes the fill cursor
    }
    __syncthreads();
    for (int i = base + t; i < end; i += 256) {
        unsigned int p = pairs[i];
        int pos = atomicAdd(&h[p >> 16], 1);
        col[pos] = (int)(p & 0xFFFFu);
    }
}

// K6: one wave per dst node, 4 groups x 16 lanes; each lane owns 8 row elems
// (16B bf16 load per edge); 4 independent row-gathers in flight per iteration.
__global__ void k_gather(const unsigned int* __restrict__ xn_bf,
                         const float* __restrict__ norm,
                         const int* __restrict__ row_ptr,
                         const int* __restrict__ col,
                         const float* __restrict__ beta_p,
                         float* __restrict__ out) {
    int wave = (blockIdx.x * blockDim.x + threadIdx.x) >> 6;
    int lane = threadIdx.x & 63;
    if (wave >= NN) return;
    int j = lane & 15;
    int g = lane >> 4;
    float beta = beta_p[0];
    float c = -fabsf(beta);

    uint4 du = ((const uint4*)(xn_bf + (size_t)wave * 64))[j];
    float xd[8];
    #pragma unroll
    for (int q = 0; q < 4; ++q) {
        unsigned int u = (&du.x)[q];
        xd[2 * q]     = bflo(u);
        xd[2 * q + 1] = bfhi(u);
    }

    float acc[8] = {0.f, 0.f, 0.f, 0.f, 0.f, 0.f, 0.f, 0.f};
    float ssum = 0.f;
    int b0 = row_ptr[wave], b1 = row_ptr[wave + 1];

    #pragma unroll 2
    for (int k = b0 + g; k < b1; k += 4) {
        int src = col[k];
        uint4 su = ((const uint4*)(xn_bf + (size_t)src * 64))[j];
        float nrm = norm[src];
        float xs[8];
        #pragma unroll
        for (int q = 0; q < 4; ++q) {
            unsigned int u = (&su.x)[q];
            xs[2 * q]     = bflo(u);
            xs[2 * q + 1] = bfhi(u);
        }
        float dot = 0.f;
        #pragma unroll
        for (int q = 0; q < 8; ++q) dot = fmaf(xd[q], xs[q], dot);
        dot += __shfl_xor(dot, 1);
        dot += __shfl_xor(dot, 2);
        dot += __shfl_xor(dot, 4);
        dot += __shfl_xor(dot, 8);
        float e = __expf(fmaf(beta, dot, c));
        ssum += e;
        float w = e * nrm;
        #pragma unroll
        for (int q = 0; q < 8; ++q) acc[q] = fmaf(w, xs[q], acc[q]);
    }

    ssum += __shfl_xor(ssum, 16);
    ssum += __shfl_xor(ssum, 32);
    #pragma unroll
    for (int q = 0; q < 8; ++q) {
        acc[q] += __shfl_xor(acc[q], 16);
        acc[q] += __shfl_xor(acc[q], 32);
    }

    float e_self = __expf(beta + c);
    ssum += e_self;
    float wsl = e_self * norm[wave];
    #pragma unroll
    for (int q = 0; q < 8; ++q) acc[q] = fmaf(wsl, xd[q], acc[q]);

    if (g == 0) {
        float inv = 1.0f / ssum;
        float4 o0, o1;
        o0.x = fmaxf(0.f, acc[0] * inv); o0.y = fmaxf(0.f, acc[1] * inv);
        o0.z = fmaxf(0.f, acc[2] * inv); o0.w = fmaxf(0.f, acc[3] * inv);
        o1.x = fmaxf(0.f, acc[4] * inv); o1.y = fmaxf(0.f, acc[5] * inv);
        o1.z = fmaxf(0.f, acc[6] * inv); o1.w = fmaxf(0.f, acc[7] * inv);
        float4* op = (float4*)(out + (size_t)wave * DF + 8 * j);
        op[0] = o0;
        op[1] = o1;
    }
}

extern "C" void kernel_launch(void* const* d_in, const int* in_sizes, int n_in,
                              void* d_out, int out_size, void* d_ws, size_t ws_size,
                              hipStream_t stream) {
    const float* x    = (const float*)d_in[0];   // fp32 [NN*DF]
    const float* beta = (const float*)d_in[1];   // fp32 [1]
    const int*   ei   = (const int*)d_in[2];     // int32 [2*NE]
    float*       out  = (float*)d_out;           // fp32 [NN*DF]

    // workspace layout (bytes), total ~26.5 MiB:
    char* ws = (char*)d_ws;
    unsigned int* xn_bf = (unsigned int*)ws;                  // 12,800,000
    float* norm    = (float*)(ws + 12800000);                 //    200,000
    int*   whist   = (int*)  (ws + 13000000);                 // NB*NWG*4 = 512,000
    int*   btotal  = (int*)  (ws + 13512000);                 //      1,000 (+pad)
    int*   bbase   = (int*)  (ws + 13513008);                 //      1,000 (+pad)
    int*   row_ptr = (int*)  (ws + 13514016);                 // (NN+1)*4 = 200,004
    unsigned int* pairs = (unsigned int*)(ws + 13714032);     // NE*4 = 6,400,000
    int*   col     = (int*)  (ws + 20114032);                 // NE*4 = 6,400,000

    k_norm   <<<(NN * 64 + 255) / 256, 256, 0, stream>>>(x, xn_bf, norm);
    k_count  <<<NWG,  256, 0, stream>>>(ei + NE, whist);
    k_scan_wg<<<NB,   NWG, 0, stream>>>(whist, btotal);
    k_scan_bk<<<1,    256, 0, stream>>>(btotal, bbase, row_ptr);
    k_part   <<<NWG,  256, 0, stream>>>(ei, whist, bbase, pairs);
    k_build  <<<NB,   256, 0, stream>>>(pairs, bbase, row_ptr, col);
    k_gather <<<(NN * 64 + 255) / 256, 256, 0, stream>>>(xn_bf, norm, row_ptr, col, beta, out);
}

// Round 6
// 189.396 us; speedup vs baseline: 7.8550x; 1.0469x over previous
//
#include <hip/hip_runtime.h>

#define NN 50000
#define NE 1600000
#define DF 128
#define NB 250      // coarse buckets
#define BSZ 200     // dst nodes per bucket  (NB*BSZ == NN)
#define NWG 512     // partition workgroups
#define CHK 3125    // edges per partition wg (NWG*CHK == NE)
#define NBN 12500   // norm blocks (4 waves each -> NN waves)

static __device__ __forceinline__ float bflo(unsigned int u) {
    unsigned int v = u << 16; float f; __builtin_memcpy(&f, &v, 4); return f;
}
static __device__ __forceinline__ float bfhi(unsigned int u) {
    unsigned int v = u & 0xFFFF0000u; float f; __builtin_memcpy(&f, &v, 4); return f;
}
static __device__ __forceinline__ unsigned int f2bf(float f) {   // RNE, low 16 bits
    unsigned int u; __builtin_memcpy(&u, &f, 4);
    u += 0x7FFFu + ((u >> 16) & 1u);
    return u >> 16;
}

// ---------------------------------------------------------------------------
// K1 (fused, disjoint block ranges):
//  blocks [0,NBN):       one wave per node: xn_bf = bf16(x * rsqrt(max(ss,eps^2))),
//                        norm = ||x|| (smooth ->0). Softmax later shifts by the
//                        constant |beta| (exact by shift-invariance; self-loop
//                        keeps every denominator >= exp(-2|beta|) > 0).
//  blocks [NBN,NBN+NWG): per-wg LDS histogram of coarse dst buckets.
// ---------------------------------------------------------------------------
__global__ void k_norm_count(const float* __restrict__ x,
                             const int* __restrict__ ei,
                             unsigned int* __restrict__ xn_bf,
                             float* __restrict__ norm,
                             int* __restrict__ whist) {
    if (blockIdx.x < NBN) {
        int wave = (blockIdx.x * 256 + threadIdx.x) >> 6;
        int lane = threadIdx.x & 63;
        float2 v = ((const float2*)(x + (size_t)wave * DF))[lane];
        float ss = v.x * v.x + v.y * v.y;
        #pragma unroll
        for (int m = 1; m < 64; m <<= 1) ss += __shfl_xor(ss, m);
        float rinv = rsqrtf(fmaxf(ss, 1e-24f));
        xn_bf[(size_t)wave * 64 + lane] = (f2bf(v.y * rinv) << 16) | f2bf(v.x * rinv);
        if (lane == 0) norm[wave] = ss * rinv;
    } else {
        __shared__ int h[NB];
        int wg = blockIdx.x - NBN, t = threadIdx.x;
        if (t < NB) h[t] = 0;
        __syncthreads();
        int c0 = wg * CHK;
        const int* dstp = ei + NE + c0;
        for (int i = t; i < CHK; i += 256) atomicAdd(&h[dstp[i] / BSZ], 1);
        __syncthreads();
        if (t < NB) whist[t * NWG + wg] = h[t];
    }
}

// K2: per-bucket exclusive scan across the 512 wg counts; bucket totals out.
__global__ void k_scan_wg(int* __restrict__ whist, int* __restrict__ btotal) {
    __shared__ int sm[NWG];
    int b = blockIdx.x, t = threadIdx.x;
    int v = whist[b * NWG + t];
    sm[t] = v;
    __syncthreads();
    #pragma unroll
    for (int off = 1; off < NWG; off <<= 1) {
        int a = (t >= off) ? sm[t - off] : 0;
        __syncthreads();
        sm[t] += a;
        __syncthreads();
    }
    whist[b * NWG + t] = sm[t] - v;          // exclusive within bucket
    if (t == NWG - 1) btotal[b] = sm[t];
}

// K3: partition edges into bucket-sorted packed records (local_dst<<16 | src).
// Bucket bases recomputed inline from btotal (250-elem LDS scan) — no extra
// dispatch. Each (wg,bucket) region is exclusively owned -> LDS cursors only.
__global__ void k_part(const int* __restrict__ ei, const int* __restrict__ whist,
                       const int* __restrict__ btotal, unsigned int* __restrict__ pairs) {
    __shared__ int sm[256];
    __shared__ int cur[NB];
    int wg = blockIdx.x, t = threadIdx.x;
    int v = (t < NB) ? btotal[t] : 0;
    sm[t] = v;
    __syncthreads();
    #pragma unroll
    for (int off = 1; off < 256; off <<= 1) {
        int a = (t >= off) ? sm[t - off] : 0;
        __syncthreads();
        sm[t] += a;
        __syncthreads();
    }
    if (t < NB) cur[t] = (sm[t] - v) + whist[t * NWG + wg];
    __syncthreads();
    int c0 = wg * CHK;
    for (int i = t; i < CHK; i += 256) {
        int src = ei[c0 + i];
        int dst = ei[NE + c0 + i];
        int b = dst / BSZ;
        int pos = atomicAdd(&cur[b], 1);
        pairs[pos] = ((unsigned int)(dst - b * BSZ) << 16) | (unsigned int)src;
    }
}

// K4: one wg per bucket: inline bucket-base scan, LDS hist over its 200 dst,
// LDS scan -> row_ptr, then LDS-cursor fill of col. col packs the source-row
// norm (bf16) in the high 16 bits: col[k] = f2bf(norm[src])<<16 | src, so the
// gather's hot loop needs no separate norm load. No global atomics.
__global__ void k_build(const unsigned int* __restrict__ pairs,
                        const int* __restrict__ btotal,
                        const float* __restrict__ norm,
                        int* __restrict__ row_ptr, unsigned int* __restrict__ col) {
    __shared__ int sc[256];
    __shared__ int h[BSZ];
    __shared__ int sbase, slen;
    int b = blockIdx.x, t = threadIdx.x;
    int v = (t < NB) ? btotal[t] : 0;
    sc[t] = v;
    __syncthreads();
    #pragma unroll
    for (int off = 1; off < 256; off <<= 1) {
        int a = (t >= off) ? sc[t - off] : 0;
        __syncthreads();
        sc[t] += a;
        __syncthreads();
    }
    if (t == b) { sbase = sc[t] - v; slen = v; }
    if (t < BSZ) h[t] = 0;
    __syncthreads();
    int base = sbase, end = sbase + slen;
    for (int i = base + t; i < end; i += 256) atomicAdd(&h[pairs[i] >> 16], 1);
    __syncthreads();
    int own = (t < BSZ) ? h[t] : 0;
    sc[t] = own;
    __syncthreads();
    #pragma unroll
    for (int off = 1; off < 256; off <<= 1) {
        int a = (t >= off) ? sc[t - off] : 0;
        __syncthreads();
        sc[t] += a;
        __syncthreads();
    }
    if (t < BSZ) {
        int excl = base + sc[t] - own;
        row_ptr[b * BSZ + t] = excl;
        h[t] = excl;                          // becomes the fill cursor
    }
    if (b == 0 && t == 0) row_ptr[NN] = NE;
    __syncthreads();
    for (int i = base + t; i < end; i += 256) {
        unsigned int p = pairs[i];
        unsigned int src = p & 0xFFFFu;
        int pos = atomicAdd(&h[p >> 16], 1);
        col[pos] = (f2bf(norm[src]) << 16) | src;
    }
}

// K5: one wave per dst node, 4 groups x 16 lanes; per edge: one packed 4B
// (norm|src) load + one 16B bf16 row load; unroll 4 keeps ~8 gathers in flight.
__global__ void k_gather(const unsigned int* __restrict__ xn_bf,
                         const float* __restrict__ norm,
                         const int* __restrict__ row_ptr,
                         const unsigned int* __restrict__ col,
                         const float* __restrict__ beta_p,
                         float* __restrict__ out) {
    int wave = (blockIdx.x * blockDim.x + threadIdx.x) >> 6;
    int lane = threadIdx.x & 63;
    if (wave >= NN) return;
    int j = lane & 15;
    int g = lane >> 4;
    float beta = beta_p[0];
    float c = -fabsf(beta);

    uint4 du = ((const uint4*)(xn_bf + (size_t)wave * 64))[j];
    float xd[8];
    #pragma unroll
    for (int q = 0; q < 4; ++q) {
        unsigned int u = (&du.x)[q];
        xd[2 * q]     = bflo(u);
        xd[2 * q + 1] = bfhi(u);
    }

    float acc[8] = {0.f, 0.f, 0.f, 0.f, 0.f, 0.f, 0.f, 0.f};
    float ssum = 0.f;
    int b0 = row_ptr[wave], b1 = row_ptr[wave + 1];

    #pragma unroll 4
    for (int k = b0 + g; k < b1; k += 4) {
        unsigned int p = col[k];                              // group-uniform
        unsigned int src = p & 0xFFFFu;
        float nrm = bfhi(p);                                  // bf16 norm, free
        uint4 su = ((const uint4*)(xn_bf + (size_t)src * 64))[j];
        float xs[8];
        #pragma unroll
        for (int q = 0; q < 4; ++q) {
            unsigned int u = (&su.x)[q];
            xs[2 * q]     = bflo(u);
            xs[2 * q + 1] = bfhi(u);
        }
        float dot = 0.f;
        #pragma unroll
        for (int q = 0; q < 8; ++q) dot = fmaf(xd[q], xs[q], dot);
        dot += __shfl_xor(dot, 1);
        dot += __shfl_xor(dot, 2);
        dot += __shfl_xor(dot, 4);
        dot += __shfl_xor(dot, 8);
        float e = __expf(fmaf(beta, dot, c));
        ssum += e;
        float w = e * nrm;
        #pragma unroll
        for (int q = 0; q < 8; ++q) acc[q] = fmaf(w, xs[q], acc[q]);
    }

    ssum += __shfl_xor(ssum, 16);
    ssum += __shfl_xor(ssum, 32);
    #pragma unroll
    for (int q = 0; q < 8; ++q) {
        acc[q] += __shfl_xor(acc[q], 16);
        acc[q] += __shfl_xor(acc[q], 32);
    }

    // self-loop (cos = 1): e_self = exp(beta - |beta|), message e_self * x_dst
    float e_self = __expf(beta + c);
    ssum += e_self;
    float wsl = e_self * norm[wave];
    #pragma unroll
    for (int q = 0; q < 8; ++q) acc[q] = fmaf(wsl, xd[q], acc[q]);

    if (g == 0) {
        float inv = 1.0f / ssum;
        float4 o0, o1;
        o0.x = fmaxf(0.f, acc[0] * inv); o0.y = fmaxf(0.f, acc[1] * inv);
        o0.z = fmaxf(0.f, acc[2] * inv); o0.w = fmaxf(0.f, acc[3] * inv);
        o1.x = fmaxf(0.f, acc[4] * inv); o1.y = fmaxf(0.f, acc[5] * inv);
        o1.z = fmaxf(0.f, acc[6] * inv); o1.w = fmaxf(0.f, acc[7] * inv);
        float4* op = (float4*)(out + (size_t)wave * DF + 8 * j);
        op[0] = o0;
        op[1] = o1;
    }
}

extern "C" void kernel_launch(void* const* d_in, const int* in_sizes, int n_in,
                              void* d_out, int out_size, void* d_ws, size_t ws_size,
                              hipStream_t stream) {
    const float* x    = (const float*)d_in[0];   // fp32 [NN*DF]
    const float* beta = (const float*)d_in[1];   // fp32 [1]
    const int*   ei   = (const int*)d_in[2];     // int32 [2*NE]
    float*       out  = (float*)d_out;           // fp32 [NN*DF]

    // workspace layout (bytes), total ~26.5 MiB:
    char* ws = (char*)d_ws;
    unsigned int* xn_bf = (unsigned int*)ws;                  // 12,800,000
    float* norm    = (float*)(ws + 12800000);                 //    200,000
    int*   whist   = (int*)  (ws + 13000000);                 // NB*NWG*4 = 512,000
    int*   btotal  = (int*)  (ws + 13512000);                 //      1,000 (+pad)
    int*   row_ptr = (int*)  (ws + 13513024);                 // (NN+1)*4 = 200,004
    unsigned int* pairs = (unsigned int*)(ws + 13713040);     // NE*4 = 6,400,000
    unsigned int* col   = (unsigned int*)(ws + 20113040);     // NE*4 = 6,400,000

    k_norm_count<<<NBN + NWG, 256, 0, stream>>>(x, ei, xn_bf, norm, whist);
    k_scan_wg   <<<NB,        NWG, 0, stream>>>(whist, btotal);
    k_part      <<<NWG,       256, 0, stream>>>(ei, whist, btotal, pairs);
    k_build     <<<NB,        256, 0, stream>>>(pairs, btotal, norm, row_ptr, col);
    k_gather    <<<(NN * 64 + 255) / 256, 256, 0, stream>>>(xn_bf, norm, row_ptr, col, beta, out);
}